// Round 23
// baseline (141.388 us; speedup 1.0000x reference)
//
#include <hip/hip_runtime.h>
#include <hip/hip_bf16.h>
#include <cstdint>

#define NTOT 73728      // B*H*W = 32*48*48
#define CTOT 512
#define MGRP 128        // members per group
#define EPSV 1e-7f

typedef float4 f4;
typedef __attribute__((ext_vector_type(8))) short bf16x8;   // 8 bf16 (4 VGPRs)
typedef __attribute__((ext_vector_type(2))) float f32x2;
typedef __attribute__((ext_vector_type(4))) float f32x4;
typedef __attribute__((ext_vector_type(16))) float f32x16;

__device__ __forceinline__ f4 ld4(const float* p){ return *(const f4*)p; }

__device__ __forceinline__ ushort f2bf(float f){  // RNE fp32 -> bf16
    uint32_t u = __builtin_bit_cast(uint32_t, f);
    uint32_t r = (u + 0x7FFFu + ((u >> 16) & 1u)) >> 16;
    return (ushort)r;
}
__device__ __forceinline__ float bfval(ushort h){
    return __builtin_bit_cast(float, (uint32_t)h << 16);
}
__device__ __forceinline__ uint32_t pk2(float a, float b){   // HW v_cvt_pk_bf16_f32
    __hip_bfloat162 h = __float22bfloat162_rn(make_float2(a, b));
    uint32_t u; __builtin_memcpy(&u, &h, 4);
    return u;
}
__device__ __forceinline__ bf16x8 pack8(const float v[8]) {
    union { bf16x8 b; uint32_t u[4]; } r;
#pragma unroll
    for (int i = 0; i < 4; ++i) r.u[i] = pk2(v[2*i], v[2*i+1]);
    return r.b;
}

// swizzled 128x128 bf16 matrix helpers (16B slots, slot ^= row&15)
__device__ __forceinline__ int mofs(int row, int col){
    return row * 128 + (((col >> 3) ^ (row & 15)) * 8) + (col & 7);
}
__device__ __forceinline__ bf16x8 mfrag(const ushort* M, int row, int ks, int h2){
    int slot = (ks * 2 + h2) ^ (row & 15);
    return *(const bf16x8*)&M[row * 128 + slot * 8];
}

// ---------------- K1: Sxx partials (bf16) — nchunk=256 for 4 blocks/CU ----------------
// grid (nchunk=256, 4), block 256 (4 waves 2x2; wave tile 64x64 of 128x128).
// LDS fp32 k-quad-interleaved, dbuf, 1 barrier/tile; 4 coalesced ld4/thread staging.
__global__ __launch_bounds__(256) void k_cov(
    const float* __restrict__ x, ushort* __restrict__ sxxPart,
    float* __restrict__ sxPart, int nchunk, int rowsPer)
{
    const int chunk = blockIdx.x, g = blockIdx.y;
    const int t = threadIdx.x;
    const int lane = t & 63, wid = t >> 6;
    const int wr = wid >> 1, wc = wid & 1;
    const int l31 = lane & 31, hi = lane >> 5;
    const size_t rowbase = (size_t)chunk * rowsPer;

    __shared__ float xs[2][4096];   // 2 x 16 KB
    __shared__ float sxred[256];

    const int kq0  = t >> 5;
    const int schk = t & 31;
    const float* xp = x + (size_t)g * MGRP + (size_t)schk * 4;
    const int wbase = kq0 * 512 + schk * 4;

    f32x16 acc[2][2];
#pragma unroll
    for (int a = 0; a < 2; ++a)
#pragma unroll
        for (int b = 0; b < 2; ++b) acc[a][b] = (f32x16){};
    float sxa0 = 0.f, sxa1 = 0.f;

    const int niter = rowsPer / 32;
    f4 r0 = ld4(xp + (rowbase + kq0*4 + 0) * CTOT);
    f4 r1 = ld4(xp + (rowbase + kq0*4 + 1) * CTOT);
    f4 r2 = ld4(xp + (rowbase + kq0*4 + 2) * CTOT);
    f4 r3 = ld4(xp + (rowbase + kq0*4 + 3) * CTOT);

    for (int it = 0; it < niter; ++it) {
        const int cur = it & 1;
        *(f32x4*)&xs[cur][wbase +   0] = (f32x4){r0.x, r1.x, r2.x, r3.x};
        *(f32x4*)&xs[cur][wbase + 128] = (f32x4){r0.y, r1.y, r2.y, r3.y};
        *(f32x4*)&xs[cur][wbase + 256] = (f32x4){r0.z, r1.z, r2.z, r3.z};
        *(f32x4*)&xs[cur][wbase + 384] = (f32x4){r0.w, r1.w, r2.w, r3.w};
        __syncthreads();
        if (it + 1 < niter) {
            const float* np = xp + (rowbase + (size_t)(it + 1) * 32 + kq0*4) * CTOT;
            r0 = ld4(np);
            r1 = ld4(np + CTOT);
            r2 = ld4(np + 2 * CTOT);
            r3 = ld4(np + 3 * CTOT);
        }
#pragma unroll
        for (int ks = 0; ks < 2; ++ks) {
            const int rbase = (ks*4 + hi*2) * 512 + (l31 >> 2) * 4 + (l31 & 3) * 128;
            bf16x8 fa[2], fb[2];
#pragma unroll
            for (int a = 0; a < 2; ++a) {
                const int ra = rbase + (wr*16 + a*8) * 4;
                f32x4 lo = *(const f32x4*)&xs[cur][ra];
                f32x4 hi4 = *(const f32x4*)&xs[cur][ra + 512];
                float v[8] = {lo.x, lo.y, lo.z, lo.w, hi4.x, hi4.y, hi4.z, hi4.w};
                if (wc == 0) {
                    float s = v[0]+v[1]+v[2]+v[3]+v[4]+v[5]+v[6]+v[7];
                    if (a == 0) sxa0 += s; else sxa1 += s;
                }
                fa[a] = pack8(v);
            }
            if (wr != wc) {
#pragma unroll
                for (int b = 0; b < 2; ++b) {
                    const int rb = rbase + (wc*16 + b*8) * 4;
                    f32x4 lo = *(const f32x4*)&xs[cur][rb];
                    f32x4 hi4 = *(const f32x4*)&xs[cur][rb + 512];
                    float v[8] = {lo.x, lo.y, lo.z, lo.w, hi4.x, hi4.y, hi4.z, hi4.w};
                    fb[b] = pack8(v);
                }
            } else {
                fb[0] = fa[0]; fb[1] = fa[1];
            }
#pragma unroll
            for (int a = 0; a < 2; ++a)
#pragma unroll
                for (int b = 0; b < 2; ++b)
                    acc[a][b] = __builtin_amdgcn_mfma_f32_32x32x16_bf16(
                        fa[a], fb[b], acc[a][b], 0, 0, 0);
        }
    }

    ushort* op = sxxPart + ((size_t)g * nchunk + chunk) * 16384;
#pragma unroll
    for (int a = 0; a < 2; ++a)
#pragma unroll
        for (int b = 0; b < 2; ++b)
#pragma unroll
            for (int r = 0; r < 16; ++r) {
                int i = wr*64 + a*32 + (r & 3) + 8 * (r >> 2) + 4 * hi;
                int j = wc*64 + b*32 + l31;
                op[i * 128 + j] = f2bf(acc[a][b][r]);
            }

    if (wc == 0) {
        sxred[(wr*64 + l31) * 2 + hi]      = sxa0;
        sxred[(wr*64 + 32 + l31) * 2 + hi] = sxa1;
    }
    __syncthreads();
    if (t < 128)
        sxPart[((size_t)g * nchunk + chunk) * 128 + t] = sxred[t*2] + sxred[t*2 + 1];
}

// ---------------- K2: reduce bf16 Sxx partials over chunks (2 elems/thread) ---------
__global__ __launch_bounds__(256) void k_reduce(
    const ushort* __restrict__ sxxPart, float* __restrict__ gSxx, int nchunk)
{
    int g = blockIdx.y;
    int p = blockIdx.x * 256 + threadIdx.x;   // pair index 0..8191
    float s0 = 0.f, s1 = 0.f;
#pragma unroll 8
    for (int c = 0; c < nchunk; ++c) {
        uint32_t u = *(const uint32_t*)&sxxPart[((size_t)g * nchunk + c) * 16384 + 2 * p];
        s0 += bfval((ushort)(u & 0xFFFF));
        s1 += bfval((ushort)(u >> 16));
    }
    *(f32x2*)&gSxx[g * 16384 + 2 * p] = (f32x2){s0, s1};
}

// ---------------- K3 (fused): finalize + 2 NS iterations + bprime + writeW -----------
__global__ __launch_bounds__(256) void k_mid(
    const float* __restrict__ gSxx, const float* __restrict__ sxPart,
    const float* __restrict__ gamma, const float* __restrict__ beta,
    float* __restrict__ gBp, ushort* __restrict__ gWb, int nchunk)
{
    const int g = blockIdx.x;
    const int t = threadIdx.x;
    const int lane = t & 63, w = t >> 6;
    const int l31 = lane & 31, h2 = lane >> 5;

    __shared__ ushort Phi[16384], Plo[16384], Shi[16384], Thi[16384];  // 128 KB
    __shared__ float muL[128];
    __shared__ float red[256];
    __shared__ float trS;

    // ---- phase A1: mu (parallel: 128 ch x 2 chunk-halves) ----
    {
        const int ch = t & 127, half = t >> 7;
        const int c0 = half * (nchunk >> 1), c1 = c0 + (nchunk >> 1);
        float s = 0.f;
#pragma unroll 8
        for (int c = c0; c < c1; ++c)
            s += sxPart[((size_t)g * nchunk + c) * 128 + ch];
        red[t] = s;
    }
    __syncthreads();
    if (t < 128) muL[t] = (red[t] + red[t + 128]) / (float)NTOT;
    __syncthreads();

    // ---- phase A2: trace ----
    {
        float d = 0.f;
        if (t < 128) {
            float vdiag = gSxx[(size_t)g * 16384 + t * 128 + t];
            float cv = (vdiag - (float)NTOT * muL[t] * muL[t]) / ((float)NTOT - 1.f);
            d = (1.f - EPSV) * cv + EPSV;
        }
        red[t] = d;
        __syncthreads();
        for (int s = 128; s > 0; s >>= 1) {
            if (t < s) red[t] += red[t + s];
            __syncthreads();
        }
        if (t == 0) trS = red[0];
    }
    __syncthreads();

    // ---- phase A3: Sigma + P0 ----
    const float invTr = 1.f / trS;
#pragma unroll 8
    for (int e = t; e < 16384; e += 256) {
        int i = e >> 7, j = e & 127;
        float cv = (gSxx[(size_t)g * 16384 + e] - (float)NTOT * muL[i] * muL[j]) / ((float)NTOT - 1.f);
        float ce = (1.f - EPSV) * cv + ((i == j) ? EPSV : 0.f);
        float sg = ce * invTr;
        Shi[mofs(i, j)] = f2bf(sg);
        float p0 = ((i == j) ? 1.5f : 0.f) - 0.5f * sg;
        ushort ph = f2bf(p0);
        Phi[mofs(i, j)] = ph;
        Plo[mofs(i, j)] = f2bf(p0 - bfval(ph));
    }
    __syncthreads();

    // ---- phase B: 2 Newton-Schulz iterations (MFMA, hi/lo bf16) ----
    const int arow = 32 * w + l31;
#pragma unroll 1
    for (int it = 0; it < 2; ++it) {
        f32x16 t1[4];
#pragma unroll
        for (int ct = 0; ct < 4; ++ct) t1[ct] = (f32x16){};
#pragma unroll
        for (int ks = 0; ks < 8; ++ks) {
            bf16x8 ah = mfrag(Phi, arow, ks, h2);
            bf16x8 al = mfrag(Plo, arow, ks, h2);
#pragma unroll
            for (int ct = 0; ct < 4; ++ct) {
                bf16x8 bh = mfrag(Phi, ct*32 + l31, ks, h2);
                bf16x8 bl = mfrag(Plo, ct*32 + l31, ks, h2);
                t1[ct] = __builtin_amdgcn_mfma_f32_32x32x16_bf16(ah, bh, t1[ct], 0, 0, 0);
                t1[ct] = __builtin_amdgcn_mfma_f32_32x32x16_bf16(ah, bl, t1[ct], 0, 0, 0);
                t1[ct] = __builtin_amdgcn_mfma_f32_32x32x16_bf16(al, bh, t1[ct], 0, 0, 0);
            }
        }
        __syncthreads();
#pragma unroll
        for (int ct = 0; ct < 4; ++ct)
#pragma unroll
            for (int r = 0; r < 16; ++r) {
                int row = 32*w + (r & 3) + 8*(r >> 2) + 4*h2;
                Thi[mofs(row, ct*32 + l31)] = f2bf(t1[ct][r]);
            }
        __syncthreads();
        f32x16 t2[4];
#pragma unroll
        for (int ct = 0; ct < 4; ++ct) t2[ct] = (f32x16){};
#pragma unroll
        for (int ks = 0; ks < 8; ++ks) {
            bf16x8 ah = mfrag(Thi, arow, ks, h2);
#pragma unroll
            for (int ct = 0; ct < 4; ++ct) {
                bf16x8 bh = mfrag(Phi, ct*32 + l31, ks, h2);
                bf16x8 bl = mfrag(Plo, ct*32 + l31, ks, h2);
                t2[ct] = __builtin_amdgcn_mfma_f32_32x32x16_bf16(ah, bh, t2[ct], 0, 0, 0);
                t2[ct] = __builtin_amdgcn_mfma_f32_32x32x16_bf16(ah, bl, t2[ct], 0, 0, 0);
            }
        }
        __syncthreads();
#pragma unroll
        for (int ct = 0; ct < 4; ++ct)
#pragma unroll
            for (int r = 0; r < 16; ++r) {
                int row = 32*w + (r & 3) + 8*(r >> 2) + 4*h2;
                Thi[mofs(row, ct*32 + l31)] = f2bf(t2[ct][r]);
            }
        __syncthreads();
        f32x16 t3[4];
#pragma unroll
        for (int ct = 0; ct < 4; ++ct) t3[ct] = (f32x16){};
#pragma unroll
        for (int ks = 0; ks < 8; ++ks) {
            bf16x8 ah = mfrag(Thi, arow, ks, h2);
#pragma unroll
            for (int ct = 0; ct < 4; ++ct) {
                bf16x8 bh = mfrag(Shi, ct*32 + l31, ks, h2);
                t3[ct] = __builtin_amdgcn_mfma_f32_32x32x16_bf16(ah, bh, t3[ct], 0, 0, 0);
            }
        }
        __syncthreads();
#pragma unroll
        for (int ct = 0; ct < 4; ++ct)
#pragma unroll
            for (int r = 0; r < 16; ++r) {
                int row = 32*w + (r & 3) + 8*(r >> 2) + 4*h2;
                int o = mofs(row, ct*32 + l31);
                float pold = bfval(Phi[o]) + bfval(Plo[o]);
                float pnew = 1.5f * pold - 0.5f * t3[ct][r];
                ushort ph = f2bf(pnew);
                Phi[o] = ph;
                Plo[o] = f2bf(pnew - bfval(ph));
            }
        __syncthreads();
    }

    // ---- phase C: bprime (parallel) + writeW ----
    const float scale = rsqrtf(trS);
    {
        const int row = t & 127, half = t >> 7;
        float s = 0.f;
#pragma unroll 8
        for (int k = half * 64; k < half * 64 + 64; ++k) {
            int o = mofs(row, k);
            s += muL[k] * (bfval(Phi[o]) + bfval(Plo[o]));
        }
        red[t] = s;
    }
    __syncthreads();
    if (t < 128) {
        float s = (red[t] + red[t + 128]) * scale;
        int c = g * 128 + t;
        gBp[c] = beta[c] - gamma[c] * s;
    }
#pragma unroll 4
    for (int e2 = t; e2 < 8192; e2 += 256) {
        int row = e2 >> 6, cp = (e2 & 63) * 2;
        float sg = scale * gamma[g * 128 + row];
        int o0 = mofs(row, cp), o1 = mofs(row, cp + 1);
        float v0 = (bfval(Phi[o0]) + bfval(Plo[o0])) * sg;
        float v1 = (bfval(Phi[o1]) + bfval(Plo[o1])) * sg;
        *(uint32_t*)&gWb[(size_t)g * 16384 + row * 128 + cp] = pk2(v0, v1);
    }
}

// ---------------- K7: out = (bf16(X) @ W'') + beta'  (gamma folded into W'') ----------
__global__ __launch_bounds__(256) void k_apply(
    const float* __restrict__ x, const ushort* __restrict__ gWb,
    const float* __restrict__ gBp, float* __restrict__ out)
{
    const int g = blockIdx.y;
    const int t = threadIdx.x, lane = t & 63, w = t >> 6;
    const int l31 = lane & 31, hi = lane >> 5;

    __shared__ ushort Wl[16384];

    {
        const uint4* src = (const uint4*)(gWb + (size_t)g * 16384);
#pragma unroll
        for (int q = 0; q < 8; ++q) {
            int i = q * 256 + t;
            int row = i >> 4, s = i & 15;
            uint4 v = src[i];
            *(uint4*)&Wl[row * 128 + ((s ^ (row & 15)) * 8)] = v;
        }
    }
    __syncthreads();

    float bp[4];
#pragma unroll
    for (int ct = 0; ct < 4; ++ct)
        bp[ct] = gBp[g * MGRP + ct * 32 + l31];

    const int base = (blockIdx.x * 4 + w) * 64;
    const float* ap = x + (size_t)(base + l31) * CTOT + g * MGRP + hi * 8;

    f4 st0[8], st1[8];
#pragma unroll
    for (int ks = 0; ks < 8; ++ks) {
        st0[ks] = ld4(ap + ks * 16);
        st1[ks] = ld4(ap + ks * 16 + 4);
    }

#pragma unroll
    for (int tile = 0; tile < 2; ++tile) {
        bf16x8 af[8];
#pragma unroll
        for (int ks = 0; ks < 8; ++ks) {
            union { bf16x8 b; uint32_t u[4]; } cv;
            cv.u[0] = pk2(st0[ks].x, st0[ks].y);
            cv.u[1] = pk2(st0[ks].z, st0[ks].w);
            cv.u[2] = pk2(st1[ks].x, st1[ks].y);
            cv.u[3] = pk2(st1[ks].z, st1[ks].w);
            af[ks] = cv.b;
        }
        if (tile < 1) {
            const float* np = ap + (size_t)32 * CTOT;
#pragma unroll
            for (int ks = 0; ks < 8; ++ks) {
                st0[ks] = ld4(np + ks * 16);
                st1[ks] = ld4(np + ks * 16 + 4);
            }
        }
        const int s0 = base + tile * 32;
#pragma unroll
        for (int ct = 0; ct < 4; ++ct) {
            const int row = ct * 32 + l31;
            f32x16 acc = {};
#pragma unroll
            for (int ks = 0; ks < 8; ++ks) {
                int slot = (ks * 2 + hi) ^ (row & 15);
                bf16x8 wf = *(const bf16x8*)&Wl[row * 128 + slot * 8];
                acc = __builtin_amdgcn_mfma_f32_32x32x16_bf16(af[ks], wf, acc, 0, 0, 0);
            }
#pragma unroll
            for (int r = 0; r < 16; ++r) {
                int orow = s0 + (r & 3) + 8 * (r >> 2) + 4 * hi;
                float val = acc[r] + bp[ct];
                __builtin_nontemporal_store(val,
                    &out[(size_t)orow * CTOT + g * MGRP + ct * 32 + l31]);
            }
        }
    }
}

// ---------------- launch ----------------
extern "C" void kernel_launch(void* const* d_in, const int* in_sizes, int n_in,
                              void* d_out, int out_size, void* d_ws, size_t ws_size,
                              hipStream_t stream)
{
    const float* x     = (const float*)d_in[0];
    const float* gamma = (const float*)d_in[1];
    const float* beta  = (const float*)d_in[2];
    float* out = (float*)d_out;
    float* ws  = (float*)d_ws;

    int nchunk = 256;   // rowsPer = 288 (divisible by 32); 1024 blocks = 4/CU
    auto need = [](int nc) -> size_t {
        return ((size_t)nc * 4 * 8192 + (size_t)nc * 4 * 128 +
                4 * 16384 + 512 + 32768) * 4;
    };
    while (nchunk > 16 && need(nchunk) > ws_size) nchunk >>= 1;
    int rowsPer = NTOT / nchunk;

    size_t off = 0;
    ushort* sxxPart = (ushort*)(ws + off); off += (size_t)nchunk * 4 * 8192;  // bf16 partials
    float* sxPart  = ws + off; off += (size_t)nchunk * 4 * 128;
    float* gSxx    = ws + off; off += 4 * 16384;
    float* gBp     = ws + off; off += 512;
    ushort* gWb    = (ushort*)(ws + off); off += 32768;

    k_cov<<<dim3(nchunk, 4), 256, 0, stream>>>(x, sxxPart, sxPart, nchunk, rowsPer);
    k_reduce<<<dim3(32, 4), 256, 0, stream>>>(sxxPart, gSxx, nchunk);
    k_mid<<<4, 256, 0, stream>>>(gSxx, sxPart, gamma, beta, gBp, gWb, nchunk);
    k_apply<<<dim3(288, 4), 256, 0, stream>>>(x, gWb, gBp, out);
}

// Round 24
// 127.115 us; speedup vs baseline: 1.1123x; 1.1123x over previous
//
#include <hip/hip_runtime.h>
#include <hip/hip_bf16.h>
#include <cstdint>

#define NTOT 73728      // B*H*W = 32*48*48
#define CTOT 512
#define MGRP 128        // members per group
#define EPSV 1e-7f

typedef float4 f4;
typedef __attribute__((ext_vector_type(8))) short bf16x8;   // 8 bf16 (4 VGPRs)
typedef __attribute__((ext_vector_type(2))) float f32x2;
typedef __attribute__((ext_vector_type(4))) float f32x4;
typedef __attribute__((ext_vector_type(16))) float f32x16;

__device__ __forceinline__ f4 ld4(const float* p){ return *(const f4*)p; }

__device__ __forceinline__ ushort f2bf(float f){  // RNE fp32 -> bf16
    uint32_t u = __builtin_bit_cast(uint32_t, f);
    uint32_t r = (u + 0x7FFFu + ((u >> 16) & 1u)) >> 16;
    return (ushort)r;
}
__device__ __forceinline__ float bfval(ushort h){
    return __builtin_bit_cast(float, (uint32_t)h << 16);
}
__device__ __forceinline__ uint32_t pk2(float a, float b){   // HW v_cvt_pk_bf16_f32
    __hip_bfloat162 h = __float22bfloat162_rn(make_float2(a, b));
    uint32_t u; __builtin_memcpy(&u, &h, 4);
    return u;
}
__device__ __forceinline__ bf16x8 pack8(const float v[8]) {
    union { bf16x8 b; uint32_t u[4]; } r;
#pragma unroll
    for (int i = 0; i < 4; ++i) r.u[i] = pk2(v[2*i], v[2*i+1]);
    return r.b;
}

// swizzled 128x128 bf16 matrix helpers (16B slots, slot ^= row&15)
__device__ __forceinline__ int mofs(int row, int col){
    return row * 128 + (((col >> 3) ^ (row & 15)) * 8) + (col & 7);
}
__device__ __forceinline__ bf16x8 mfrag(const ushort* M, int row, int ks, int h2){
    int slot = (ks * 2 + h2) ^ (row & 15);
    return *(const bf16x8*)&M[row * 128 + slot * 8];
}

// ---------------- K1: Sxx partials (bf16) — r20 structure, nchunk=128 ----------------
// grid (nchunk=128, 4), block 256 (4 waves 2x2; wave tile 64x64 of 128x128).
// LDS fp32 k-quad-interleaved, dbuf, 1 barrier/tile; 4 coalesced ld4/thread staging.
__global__ __launch_bounds__(256) void k_cov(
    const float* __restrict__ x, ushort* __restrict__ sxxPart,
    float* __restrict__ sxPart, int nchunk, int rowsPer)
{
    const int chunk = blockIdx.x, g = blockIdx.y;
    const int t = threadIdx.x;
    const int lane = t & 63, wid = t >> 6;
    const int wr = wid >> 1, wc = wid & 1;
    const int l31 = lane & 31, hi = lane >> 5;
    const size_t rowbase = (size_t)chunk * rowsPer;

    __shared__ float xs[2][4096];   // 2 x 16 KB
    __shared__ float sxred[256];

    const int kq0  = t >> 5;
    const int schk = t & 31;
    const float* xp = x + (size_t)g * MGRP + (size_t)schk * 4;
    const int wbase = kq0 * 512 + schk * 4;

    f32x16 acc[2][2];
#pragma unroll
    for (int a = 0; a < 2; ++a)
#pragma unroll
        for (int b = 0; b < 2; ++b) acc[a][b] = (f32x16){};
    float sxa0 = 0.f, sxa1 = 0.f;

    const int niter = rowsPer / 32;
    f4 r0 = ld4(xp + (rowbase + kq0*4 + 0) * CTOT);
    f4 r1 = ld4(xp + (rowbase + kq0*4 + 1) * CTOT);
    f4 r2 = ld4(xp + (rowbase + kq0*4 + 2) * CTOT);
    f4 r3 = ld4(xp + (rowbase + kq0*4 + 3) * CTOT);

    for (int it = 0; it < niter; ++it) {
        const int cur = it & 1;
        *(f32x4*)&xs[cur][wbase +   0] = (f32x4){r0.x, r1.x, r2.x, r3.x};
        *(f32x4*)&xs[cur][wbase + 128] = (f32x4){r0.y, r1.y, r2.y, r3.y};
        *(f32x4*)&xs[cur][wbase + 256] = (f32x4){r0.z, r1.z, r2.z, r3.z};
        *(f32x4*)&xs[cur][wbase + 384] = (f32x4){r0.w, r1.w, r2.w, r3.w};
        __syncthreads();
        if (it + 1 < niter) {
            const float* np = xp + (rowbase + (size_t)(it + 1) * 32 + kq0*4) * CTOT;
            r0 = ld4(np);
            r1 = ld4(np + CTOT);
            r2 = ld4(np + 2 * CTOT);
            r3 = ld4(np + 3 * CTOT);
        }
#pragma unroll
        for (int ks = 0; ks < 2; ++ks) {
            const int rbase = (ks*4 + hi*2) * 512 + (l31 >> 2) * 4 + (l31 & 3) * 128;
            bf16x8 fa[2], fb[2];
#pragma unroll
            for (int a = 0; a < 2; ++a) {
                const int ra = rbase + (wr*16 + a*8) * 4;
                f32x4 lo = *(const f32x4*)&xs[cur][ra];
                f32x4 hi4 = *(const f32x4*)&xs[cur][ra + 512];
                float v[8] = {lo.x, lo.y, lo.z, lo.w, hi4.x, hi4.y, hi4.z, hi4.w};
                if (wc == 0) {
                    float s = v[0]+v[1]+v[2]+v[3]+v[4]+v[5]+v[6]+v[7];
                    if (a == 0) sxa0 += s; else sxa1 += s;
                }
                fa[a] = pack8(v);
            }
            if (wr != wc) {
#pragma unroll
                for (int b = 0; b < 2; ++b) {
                    const int rb = rbase + (wc*16 + b*8) * 4;
                    f32x4 lo = *(const f32x4*)&xs[cur][rb];
                    f32x4 hi4 = *(const f32x4*)&xs[cur][rb + 512];
                    float v[8] = {lo.x, lo.y, lo.z, lo.w, hi4.x, hi4.y, hi4.z, hi4.w};
                    fb[b] = pack8(v);
                }
            } else {
                fb[0] = fa[0]; fb[1] = fa[1];
            }
#pragma unroll
            for (int a = 0; a < 2; ++a)
#pragma unroll
                for (int b = 0; b < 2; ++b)
                    acc[a][b] = __builtin_amdgcn_mfma_f32_32x32x16_bf16(
                        fa[a], fb[b], acc[a][b], 0, 0, 0);
        }
    }

    ushort* op = sxxPart + ((size_t)g * nchunk + chunk) * 16384;
#pragma unroll
    for (int a = 0; a < 2; ++a)
#pragma unroll
        for (int b = 0; b < 2; ++b)
#pragma unroll
            for (int r = 0; r < 16; ++r) {
                int i = wr*64 + a*32 + (r & 3) + 8 * (r >> 2) + 4 * hi;
                int j = wc*64 + b*32 + l31;
                op[i * 128 + j] = f2bf(acc[a][b][r]);
            }

    if (wc == 0) {
        sxred[(wr*64 + l31) * 2 + hi]      = sxa0;
        sxred[(wr*64 + 32 + l31) * 2 + hi] = sxa1;
    }
    __syncthreads();
    if (t < 128)
        sxPart[((size_t)g * nchunk + chunk) * 128 + t] = sxred[t*2] + sxred[t*2 + 1];
}

// ---------------- K2: reduce bf16 Sxx partials over chunks (2 elems/thread) ---------
__global__ __launch_bounds__(256) void k_reduce(
    const ushort* __restrict__ sxxPart, float* __restrict__ gSxx, int nchunk)
{
    int g = blockIdx.y;
    int p = blockIdx.x * 256 + threadIdx.x;   // pair index 0..8191
    float s0 = 0.f, s1 = 0.f;
#pragma unroll 8
    for (int c = 0; c < nchunk; ++c) {
        uint32_t u = *(const uint32_t*)&sxxPart[((size_t)g * nchunk + c) * 16384 + 2 * p];
        s0 += bfval((ushort)(u & 0xFFFF));
        s1 += bfval((ushort)(u >> 16));
    }
    *(f32x2*)&gSxx[g * 16384 + 2 * p] = (f32x2){s0, s1};
}

// ---------------- K3 (fused): finalize + 2 NS iterations + bprime + writeW -----------
__global__ __launch_bounds__(256) void k_mid(
    const float* __restrict__ gSxx, const float* __restrict__ sxPart,
    const float* __restrict__ gamma, const float* __restrict__ beta,
    float* __restrict__ gBp, ushort* __restrict__ gWb, int nchunk)
{
    const int g = blockIdx.x;
    const int t = threadIdx.x;
    const int lane = t & 63, w = t >> 6;
    const int l31 = lane & 31, h2 = lane >> 5;

    __shared__ ushort Phi[16384], Plo[16384], Shi[16384], Thi[16384];  // 128 KB
    __shared__ float muL[128];
    __shared__ float red[256];
    __shared__ float trS;

    // ---- phase A1: mu (parallel: 128 ch x 2 chunk-halves) ----
    {
        const int ch = t & 127, half = t >> 7;
        const int c0 = half * (nchunk >> 1), c1 = c0 + (nchunk >> 1);
        float s = 0.f;
#pragma unroll 8
        for (int c = c0; c < c1; ++c)
            s += sxPart[((size_t)g * nchunk + c) * 128 + ch];
        red[t] = s;
    }
    __syncthreads();
    if (t < 128) muL[t] = (red[t] + red[t + 128]) / (float)NTOT;
    __syncthreads();

    // ---- phase A2: trace ----
    {
        float d = 0.f;
        if (t < 128) {
            float vdiag = gSxx[(size_t)g * 16384 + t * 128 + t];
            float cv = (vdiag - (float)NTOT * muL[t] * muL[t]) / ((float)NTOT - 1.f);
            d = (1.f - EPSV) * cv + EPSV;
        }
        red[t] = d;
        __syncthreads();
        for (int s = 128; s > 0; s >>= 1) {
            if (t < s) red[t] += red[t + s];
            __syncthreads();
        }
        if (t == 0) trS = red[0];
    }
    __syncthreads();

    // ---- phase A3: Sigma + P0 ----
    const float invTr = 1.f / trS;
#pragma unroll 8
    for (int e = t; e < 16384; e += 256) {
        int i = e >> 7, j = e & 127;
        float cv = (gSxx[(size_t)g * 16384 + e] - (float)NTOT * muL[i] * muL[j]) / ((float)NTOT - 1.f);
        float ce = (1.f - EPSV) * cv + ((i == j) ? EPSV : 0.f);
        float sg = ce * invTr;
        Shi[mofs(i, j)] = f2bf(sg);
        float p0 = ((i == j) ? 1.5f : 0.f) - 0.5f * sg;
        ushort ph = f2bf(p0);
        Phi[mofs(i, j)] = ph;
        Plo[mofs(i, j)] = f2bf(p0 - bfval(ph));
    }
    __syncthreads();

    // ---- phase B: 2 Newton-Schulz iterations (MFMA, hi/lo bf16) ----
    const int arow = 32 * w + l31;
#pragma unroll 1
    for (int it = 0; it < 2; ++it) {
        f32x16 t1[4];
#pragma unroll
        for (int ct = 0; ct < 4; ++ct) t1[ct] = (f32x16){};
#pragma unroll
        for (int ks = 0; ks < 8; ++ks) {
            bf16x8 ah = mfrag(Phi, arow, ks, h2);
            bf16x8 al = mfrag(Plo, arow, ks, h2);
#pragma unroll
            for (int ct = 0; ct < 4; ++ct) {
                bf16x8 bh = mfrag(Phi, ct*32 + l31, ks, h2);
                bf16x8 bl = mfrag(Plo, ct*32 + l31, ks, h2);
                t1[ct] = __builtin_amdgcn_mfma_f32_32x32x16_bf16(ah, bh, t1[ct], 0, 0, 0);
                t1[ct] = __builtin_amdgcn_mfma_f32_32x32x16_bf16(ah, bl, t1[ct], 0, 0, 0);
                t1[ct] = __builtin_amdgcn_mfma_f32_32x32x16_bf16(al, bh, t1[ct], 0, 0, 0);
            }
        }
        __syncthreads();
#pragma unroll
        for (int ct = 0; ct < 4; ++ct)
#pragma unroll
            for (int r = 0; r < 16; ++r) {
                int row = 32*w + (r & 3) + 8*(r >> 2) + 4*h2;
                Thi[mofs(row, ct*32 + l31)] = f2bf(t1[ct][r]);
            }
        __syncthreads();
        f32x16 t2[4];
#pragma unroll
        for (int ct = 0; ct < 4; ++ct) t2[ct] = (f32x16){};
#pragma unroll
        for (int ks = 0; ks < 8; ++ks) {
            bf16x8 ah = mfrag(Thi, arow, ks, h2);
#pragma unroll
            for (int ct = 0; ct < 4; ++ct) {
                bf16x8 bh = mfrag(Phi, ct*32 + l31, ks, h2);
                bf16x8 bl = mfrag(Plo, ct*32 + l31, ks, h2);
                t2[ct] = __builtin_amdgcn_mfma_f32_32x32x16_bf16(ah, bh, t2[ct], 0, 0, 0);
                t2[ct] = __builtin_amdgcn_mfma_f32_32x32x16_bf16(ah, bl, t2[ct], 0, 0, 0);
            }
        }
        __syncthreads();
#pragma unroll
        for (int ct = 0; ct < 4; ++ct)
#pragma unroll
            for (int r = 0; r < 16; ++r) {
                int row = 32*w + (r & 3) + 8*(r >> 2) + 4*h2;
                Thi[mofs(row, ct*32 + l31)] = f2bf(t2[ct][r]);
            }
        __syncthreads();
        f32x16 t3[4];
#pragma unroll
        for (int ct = 0; ct < 4; ++ct) t3[ct] = (f32x16){};
#pragma unroll
        for (int ks = 0; ks < 8; ++ks) {
            bf16x8 ah = mfrag(Thi, arow, ks, h2);
#pragma unroll
            for (int ct = 0; ct < 4; ++ct) {
                bf16x8 bh = mfrag(Shi, ct*32 + l31, ks, h2);
                t3[ct] = __builtin_amdgcn_mfma_f32_32x32x16_bf16(ah, bh, t3[ct], 0, 0, 0);
            }
        }
        __syncthreads();
#pragma unroll
        for (int ct = 0; ct < 4; ++ct)
#pragma unroll
            for (int r = 0; r < 16; ++r) {
                int row = 32*w + (r & 3) + 8*(r >> 2) + 4*h2;
                int o = mofs(row, ct*32 + l31);
                float pold = bfval(Phi[o]) + bfval(Plo[o]);
                float pnew = 1.5f * pold - 0.5f * t3[ct][r];
                ushort ph = f2bf(pnew);
                Phi[o] = ph;
                Plo[o] = f2bf(pnew - bfval(ph));
            }
        __syncthreads();
    }

    // ---- phase C: bprime (parallel) + writeW ----
    const float scale = rsqrtf(trS);
    {
        const int row = t & 127, half = t >> 7;
        float s = 0.f;
#pragma unroll 8
        for (int k = half * 64; k < half * 64 + 64; ++k) {
            int o = mofs(row, k);
            s += muL[k] * (bfval(Phi[o]) + bfval(Plo[o]));
        }
        red[t] = s;
    }
    __syncthreads();
    if (t < 128) {
        float s = (red[t] + red[t + 128]) * scale;
        int c = g * 128 + t;
        gBp[c] = beta[c] - gamma[c] * s;
    }
#pragma unroll 4
    for (int e2 = t; e2 < 8192; e2 += 256) {
        int row = e2 >> 6, cp = (e2 & 63) * 2;
        float sg = scale * gamma[g * 128 + row];
        int o0 = mofs(row, cp), o1 = mofs(row, cp + 1);
        float v0 = (bfval(Phi[o0]) + bfval(Plo[o0])) * sg;
        float v1 = (bfval(Phi[o1]) + bfval(Plo[o1])) * sg;
        *(uint32_t*)&gWb[(size_t)g * 16384 + row * 128 + cp] = pk2(v0, v1);
    }
}

// ---------------- K7: out = (bf16(X) @ W'') + beta'  (gamma folded into W'') ----------
__global__ __launch_bounds__(256) void k_apply(
    const float* __restrict__ x, const ushort* __restrict__ gWb,
    const float* __restrict__ gBp, float* __restrict__ out)
{
    const int g = blockIdx.y;
    const int t = threadIdx.x, lane = t & 63, w = t >> 6;
    const int l31 = lane & 31, hi = lane >> 5;

    __shared__ ushort Wl[16384];

    {
        const uint4* src = (const uint4*)(gWb + (size_t)g * 16384);
#pragma unroll
        for (int q = 0; q < 8; ++q) {
            int i = q * 256 + t;
            int row = i >> 4, s = i & 15;
            uint4 v = src[i];
            *(uint4*)&Wl[row * 128 + ((s ^ (row & 15)) * 8)] = v;
        }
    }
    __syncthreads();

    float bp[4];
#pragma unroll
    for (int ct = 0; ct < 4; ++ct)
        bp[ct] = gBp[g * MGRP + ct * 32 + l31];

    const int base = (blockIdx.x * 4 + w) * 64;
    const float* ap = x + (size_t)(base + l31) * CTOT + g * MGRP + hi * 8;

    f4 st0[8], st1[8];
#pragma unroll
    for (int ks = 0; ks < 8; ++ks) {
        st0[ks] = ld4(ap + ks * 16);
        st1[ks] = ld4(ap + ks * 16 + 4);
    }

#pragma unroll
    for (int tile = 0; tile < 2; ++tile) {
        bf16x8 af[8];
#pragma unroll
        for (int ks = 0; ks < 8; ++ks) {
            union { bf16x8 b; uint32_t u[4]; } cv;
            cv.u[0] = pk2(st0[ks].x, st0[ks].y);
            cv.u[1] = pk2(st0[ks].z, st0[ks].w);
            cv.u[2] = pk2(st1[ks].x, st1[ks].y);
            cv.u[3] = pk2(st1[ks].z, st1[ks].w);
            af[ks] = cv.b;
        }
        if (tile < 1) {
            const float* np = ap + (size_t)32 * CTOT;
#pragma unroll
            for (int ks = 0; ks < 8; ++ks) {
                st0[ks] = ld4(np + ks * 16);
                st1[ks] = ld4(np + ks * 16 + 4);
            }
        }
        const int s0 = base + tile * 32;
#pragma unroll
        for (int ct = 0; ct < 4; ++ct) {
            const int row = ct * 32 + l31;
            f32x16 acc = {};
#pragma unroll
            for (int ks = 0; ks < 8; ++ks) {
                int slot = (ks * 2 + hi) ^ (row & 15);
                bf16x8 wf = *(const bf16x8*)&Wl[row * 128 + slot * 8];
                acc = __builtin_amdgcn_mfma_f32_32x32x16_bf16(af[ks], wf, acc, 0, 0, 0);
            }
#pragma unroll
            for (int r = 0; r < 16; ++r) {
                int orow = s0 + (r & 3) + 8 * (r >> 2) + 4 * hi;
                float val = acc[r] + bp[ct];
                __builtin_nontemporal_store(val,
                    &out[(size_t)orow * CTOT + g * MGRP + ct * 32 + l31]);
            }
        }
    }
}

// ---------------- launch ----------------
extern "C" void kernel_launch(void* const* d_in, const int* in_sizes, int n_in,
                              void* d_out, int out_size, void* d_ws, size_t ws_size,
                              hipStream_t stream)
{
    const float* x     = (const float*)d_in[0];
    const float* gamma = (const float*)d_in[1];
    const float* beta  = (const float*)d_in[2];
    float* out = (float*)d_out;
    float* ws  = (float*)d_ws;

    int nchunk = 128;   // rowsPer = 576 (divisible by 32)
    auto need = [](int nc) -> size_t {
        return ((size_t)nc * 4 * 8192 + (size_t)nc * 4 * 128 +
                4 * 16384 + 512 + 32768) * 4;
    };
    while (nchunk > 16 && need(nchunk) > ws_size) nchunk >>= 1;
    int rowsPer = NTOT / nchunk;

    size_t off = 0;
    ushort* sxxPart = (ushort*)(ws + off); off += (size_t)nchunk * 4 * 8192;  // bf16 partials
    float* sxPart  = ws + off; off += (size_t)nchunk * 4 * 128;
    float* gSxx    = ws + off; off += 4 * 16384;
    float* gBp     = ws + off; off += 512;
    ushort* gWb    = (ushort*)(ws + off); off += 32768;

    k_cov<<<dim3(nchunk, 4), 256, 0, stream>>>(x, sxxPart, sxPart, nchunk, rowsPer);
    k_reduce<<<dim3(32, 4), 256, 0, stream>>>(sxxPart, gSxx, nchunk);
    k_mid<<<4, 256, 0, stream>>>(gSxx, sxPart, gamma, beta, gBp, gWb, nchunk);
    k_apply<<<dim3(288, 4), 256, 0, stream>>>(x, gWb, gBp, out);
}